// Round 1
// baseline (258.611 us; speedup 1.0000x reference)
//
#include <hip/hip_runtime.h>

// SOM loss, MI355X. Dims fixed by setup_inputs(): B=4096, D=1024, m=n=128, T=100.
// ws layout (requires ws_size >= ~181 MB):
//   Xb   bf16[4096][1024]        @ 0          (8,388,608 B)
//   Wb   bf16[16384][1024]       @ 8388608    (33,554,432 B)
//   x2   f32[4096]               @ 41943040
//   w2   f32[16384]              @ 41959424
//   d2   bf16[4096][16384]       @ 42024960   (134,217,728 B)
//   pmin f32[4096][128]          @ 176242688
//   pidx i32[4096][128]          @ 178339840
//   bmu  i32[4096]               @ 180436992
//   lossb f32[4096]              @ 180453376   (end 180,469,760)

typedef __attribute__((ext_vector_type(8))) short short8;
typedef __attribute__((ext_vector_type(4))) float f32x4;
typedef unsigned short ushort_t;

#define B_ROWS 4096
#define DIM    1024
#define MN     16384
#define NJB    128

__device__ static inline ushort_t f32_to_bf16(float f) {
    unsigned u = __float_as_uint(f);
    u = (u + 0x7FFFu + ((u >> 16) & 1u)) >> 16;   // RTN-even
    return (ushort_t)u;
}
__device__ static inline float bf16_to_f32(ushort_t h) {
    return __uint_as_float(((unsigned)h) << 16);
}
__device__ static inline void gload_lds16(const void* g, void* l) {
    __builtin_amdgcn_global_load_lds(
        (const __attribute__((address_space(1))) unsigned*)g,
        (__attribute__((address_space(3))) unsigned*)l, 16, 0, 0);
}

// ---------- Kernel 1: f32 -> bf16 conversion + row sum-of-squares ----------
__global__ __launch_bounds__(256) void k_convert(
    const float* __restrict__ X, const float* __restrict__ W,
    ushort_t* __restrict__ Xb, ushort_t* __restrict__ Wb,
    float* __restrict__ x2, float* __restrict__ w2) {
    int row  = blockIdx.x * 4 + (threadIdx.x >> 6);
    int lane = threadIdx.x & 63;
    const float4* src;
    ushort4* dst;
    float* sq;
    if (row < B_ROWS) {
        src = (const float4*)(X + (size_t)row * DIM);
        dst = (ushort4*)(Xb + (size_t)row * DIM);
        sq  = x2 + row;
    } else {
        int r2 = row - B_ROWS;
        src = (const float4*)(W + (size_t)r2 * DIM);
        dst = (ushort4*)(Wb + (size_t)r2 * DIM);
        sq  = w2 + r2;
    }
    float s = 0.f;
    #pragma unroll
    for (int c = 0; c < 4; ++c) {
        float4 v = src[c * 64 + lane];
        s += v.x * v.x + v.y * v.y + v.z * v.z + v.w * v.w;
        ushort4 o = { f32_to_bf16(v.x), f32_to_bf16(v.y),
                      f32_to_bf16(v.z), f32_to_bf16(v.w) };
        dst[c * 64 + lane] = o;
    }
    #pragma unroll
    for (int d = 1; d < 64; d <<= 1) s += __shfl_xor(s, d);
    if (lane == 0) *sq = s;
}

// ---------- Kernel 2: bf16 MFMA GEMM -> d2 (bf16) + per-(row, jblock) min ----------
// 128x128 tile, BK=32, 4 waves (2x2), each wave 64x64 via 4x4 frags of 16x16x32.
__global__ __launch_bounds__(256) void k_gemm_d2(
    const ushort_t* __restrict__ Xb, const ushort_t* __restrict__ Wb,
    const float* __restrict__ x2, const float* __restrict__ w2,
    ushort_t* __restrict__ d2, float* __restrict__ pmin, int* __restrict__ pidx) {
    __shared__ ushort_t sA[128 * 32];
    __shared__ ushort_t sB[128 * 32];
    __shared__ float smin[128][2];
    __shared__ int   sidx[128][2];

    const int tid  = threadIdx.x;
    const int tm   = blockIdx.x & 31;   // 32 row tiles; col-tile-major order for W reuse in L2
    const int tn   = blockIdx.x >> 5;   // 128 col tiles
    const int lane = tid & 63;
    const int w    = tid >> 6;
    const int wr   = w >> 1, wc = w & 1;
    const int lr   = lane >> 4;   // 0..3
    const int lc   = lane & 15;

    // staging addresses: thread loads 16B at (row = tid>>2, col8 = (tid&3)*8)
    const int r  = tid >> 2;
    const int c8 = (tid & 3) * 8;
    const size_t aBase = (size_t)(tm * 128 + r) * DIM + c8;
    const size_t bBase = (size_t)(tn * 128 + r) * DIM + c8;

    f32x4 acc[4][4];
    #pragma unroll
    for (int i = 0; i < 4; ++i)
        #pragma unroll
        for (int j = 0; j < 4; ++j) acc[i][j] = (f32x4)0.f;

    for (int ks = 0; ks < DIM / 32; ++ks) {
        const int k0 = ks * 32;
        gload_lds16(Xb + aBase + k0,            &sA[tid * 8]);
        gload_lds16(Xb + aBase + 64 * DIM + k0, &sA[2048 + tid * 8]);
        gload_lds16(Wb + bBase + k0,            &sB[tid * 8]);
        gload_lds16(Wb + bBase + 64 * DIM + k0, &sB[2048 + tid * 8]);
        __syncthreads();   // drains vmcnt -> tile visible
        short8 a[4], b[4];
        const int koff = lr * 8;
        #pragma unroll
        for (int i = 0; i < 4; ++i)
            a[i] = *(const short8*)&sA[(wr * 64 + i * 16 + lc) * 32 + koff];
        #pragma unroll
        for (int j = 0; j < 4; ++j)
            b[j] = *(const short8*)&sB[(wc * 64 + j * 16 + lc) * 32 + koff];
        #pragma unroll
        for (int i = 0; i < 4; ++i)
            #pragma unroll
            for (int j = 0; j < 4; ++j)
                acc[i][j] = __builtin_amdgcn_mfma_f32_16x16x32_bf16(a[i], b[j], acc[i][j], 0, 0, 0);
        __syncthreads();   // all reads done before next stage overwrites
    }

    // epilogue: d2 = x2 - 2*dot + w2; store bf16; per-row min over this block's 128 cols
    const int colb = tn * 128 + wc * 64 + lc;   // global col at fj=0
    float w2c[4];
    #pragma unroll
    for (int j = 0; j < 4; ++j) w2c[j] = w2[colb + j * 16];

    #pragma unroll
    for (int i = 0; i < 4; ++i) {
        #pragma unroll
        for (int rg = 0; rg < 4; ++rg) {
            const int rloc = wr * 64 + i * 16 + lr * 4 + rg;  // row within block
            const int row  = tm * 128 + rloc;                  // global X row
            const float xx = x2[row];
            ushort_t* dst = d2 + (size_t)row * MN + colb;
            float dvv[4];
            #pragma unroll
            for (int j = 0; j < 4; ++j) {
                dvv[j] = xx - 2.f * acc[i][j][rg] + w2c[j];
                dst[j * 16] = f32_to_bf16(dvv[j]);
            }
            float mn = dvv[0]; int ix = colb;
            #pragma unroll
            for (int j = 1; j < 4; ++j)
                if (dvv[j] < mn) { mn = dvv[j]; ix = colb + j * 16; }
            // reduce across the 16 lanes sharing this row (lc dimension)
            #pragma unroll
            for (int d = 1; d < 16; d <<= 1) {
                float om = __shfl_xor(mn, d);
                int   oi = __shfl_xor(ix, d);
                if (om < mn || (om == mn && oi < ix)) { mn = om; ix = oi; }
            }
            if (lc == 0) { smin[rloc][wc] = mn; sidx[rloc][wc] = ix; }
        }
    }
    __syncthreads();
    if (tid < 128) {
        float m0 = smin[tid][0], m1 = smin[tid][1];
        int   i0 = sidx[tid][0], i1 = sidx[tid][1];
        bool take1 = (m1 < m0) || (m1 == m0 && i1 < i0);
        float mn = take1 ? m1 : m0;
        int   ix = take1 ? i1 : i0;
        int row = tm * 128 + tid;
        pmin[(size_t)row * NJB + tn] = mn;
        pidx[(size_t)row * NJB + tn] = ix;
    }
}

// ---------- Kernel 3: reduce 128 partials/row -> bmu ----------
__global__ __launch_bounds__(256) void k_argmin(
    const float* __restrict__ pmin, const int* __restrict__ pidx,
    int* __restrict__ bmu) {
    int row  = blockIdx.x * 4 + (threadIdx.x >> 6);
    int lane = threadIdx.x & 63;
    const float* pm = pmin + (size_t)row * NJB;
    const int*   pi = pidx + (size_t)row * NJB;
    float m0 = pm[lane];      int i0 = pi[lane];
    float m1 = pm[lane + 64]; int i1 = pi[lane + 64];
    if (m1 < m0 || (m1 == m0 && i1 < i0)) { m0 = m1; i0 = i1; }
    #pragma unroll
    for (int d = 1; d < 64; d <<= 1) {
        float om = __shfl_xor(m0, d);
        int   oi = __shfl_xor(i0, d);
        if (om < m0 || (om == m0 && oi < i0)) { m0 = om; i0 = oi; }
    }
    if (lane == 0) bmu[row] = i0;
}

// ---------- Kernel 4: influence-weighted row sum ----------
__global__ __launch_bounds__(256) void k_loss(
    const ushort_t* __restrict__ d2, const int* __restrict__ bmu,
    float* __restrict__ lossb) {
    __shared__ float etab[255];
    __shared__ float red[4];
    int t = threadIdx.x;
    if (t < 255) etab[t] = __expf(-(float)(t * t) * 1e-4f);  // exp(-r^2/T^2), T=100
    __syncthreads();
    int row = blockIdx.x;
    int bl = bmu[row];
    int bi = bl >> 7, bj = bl & 127;
    const ushort_t* dr = d2 + (size_t)row * MN;
    float s = 0.f;
    #pragma unroll
    for (int c = 0; c < 8; ++c) {
        int j = c * 2048 + t * 8;          // 8 consecutive cells, same grid row i
        short8 v = *(const short8*)&dr[j];
        int di = abs((j >> 7) - bi);
        int jc = j & 127;
        #pragma unroll
        for (int u = 0; u < 8; ++u) {
            int mh = di + abs(jc + u - bj);
            s += bf16_to_f32((ushort_t)v[u]) * etab[mh];
        }
    }
    #pragma unroll
    for (int d = 1; d < 64; d <<= 1) s += __shfl_xor(s, d);
    if ((t & 63) == 0) red[t >> 6] = s;
    __syncthreads();
    if (t == 0) lossb[row] = red[0] + red[1] + red[2] + red[3];
}

// ---------- Kernel 5: final deterministic reduce ----------
__global__ __launch_bounds__(256) void k_final(
    const float* __restrict__ lossb, float* __restrict__ out) {
    __shared__ float red[4];
    int t = threadIdx.x;
    float s = 0.f;
    #pragma unroll
    for (int k = 0; k < 16; ++k) s += lossb[t + k * 256];
    #pragma unroll
    for (int d = 1; d < 64; d <<= 1) s += __shfl_xor(s, d);
    if ((t & 63) == 0) red[t >> 6] = s;
    __syncthreads();
    if (t == 0) out[0] = (red[0] + red[1] + red[2] + red[3]) * (1.0f / 128.0f);
}

extern "C" void kernel_launch(void* const* d_in, const int* in_sizes, int n_in,
                              void* d_out, int out_size, void* d_ws, size_t ws_size,
                              hipStream_t stream) {
    const float* X = (const float*)d_in[0];
    const float* W = (const float*)d_in[1];
    unsigned char* ws = (unsigned char*)d_ws;
    ushort_t* Xb   = (ushort_t*)(ws);
    ushort_t* Wb   = (ushort_t*)(ws + 8388608);
    float*    x2   = (float*)(ws + 41943040);
    float*    w2   = (float*)(ws + 41959424);
    ushort_t* d2   = (ushort_t*)(ws + 42024960);
    float*    pmin = (float*)(ws + 176242688);
    int*      pidx = (int*)(ws + 178339840);
    int*      bmu  = (int*)(ws + 180436992);
    float*    lossb= (float*)(ws + 180453376);

    k_convert<<<5120, 256, 0, stream>>>(X, W, Xb, Wb, x2, w2);
    k_gemm_d2<<<4096, 256, 0, stream>>>(Xb, Wb, x2, w2, d2, pmin, pidx);
    k_argmin<<<1024, 256, 0, stream>>>(pmin, pidx, bmu);
    k_loss<<<4096, 256, 0, stream>>>(d2, bmu, lossb);
    k_final<<<1, 256, 0, stream>>>(lossb, (float*)d_out);
}

// Round 2
// 225.910 us; speedup vs baseline: 1.1448x; 1.1448x over previous
//
#include <hip/hip_runtime.h>

// SOM loss, MI355X. Dims fixed: B=4096, D=1024, m=n=128, T=100.
// ws layout:
//   Xb   bf16[4096][1024]        @ 0
//   Wb   bf16[16384][1024]       @ 8388608
//   x2   f32[4096]               @ 41943040
//   w2   f32[16384]              @ 41959424
//   d2   bf16[4096][16384]       @ 42024960
//   pmin f32[4096][64]           @ 176242688
//   pidx i32[4096][64]           @ 178339840
//   bmu  i32[4096]               @ 180436992
//   lossb f32[4096]              @ 180453376

typedef __attribute__((ext_vector_type(8))) short short8;
typedef __attribute__((ext_vector_type(4))) float f32x4;
typedef unsigned short ushort_t;

#define B_ROWS 4096
#define DIM    1024
#define MN     16384
#define NJB    64

__device__ static inline ushort_t f32_to_bf16(float f) {
    unsigned u = __float_as_uint(f);
    u = (u + 0x7FFFu + ((u >> 16) & 1u)) >> 16;   // RTN-even
    return (ushort_t)u;
}
__device__ static inline float bf16_to_f32(ushort_t h) {
    return __uint_as_float(((unsigned)h) << 16);
}
__device__ static inline void gload_lds16(const void* g, void* l) {
    __builtin_amdgcn_global_load_lds(
        (const __attribute__((address_space(1))) unsigned*)g,
        (__attribute__((address_space(3))) unsigned*)l, 16, 0, 0);
}

// ---------- Kernel 1: f32 -> bf16 conversion + row sum-of-squares ----------
__global__ __launch_bounds__(256) void k_convert(
    const float* __restrict__ X, const float* __restrict__ W,
    ushort_t* __restrict__ Xb, ushort_t* __restrict__ Wb,
    float* __restrict__ x2, float* __restrict__ w2) {
    int row  = blockIdx.x * 4 + (threadIdx.x >> 6);
    int lane = threadIdx.x & 63;
    const float4* src;
    ushort4* dst;
    float* sq;
    if (row < B_ROWS) {
        src = (const float4*)(X + (size_t)row * DIM);
        dst = (ushort4*)(Xb + (size_t)row * DIM);
        sq  = x2 + row;
    } else {
        int r2 = row - B_ROWS;
        src = (const float4*)(W + (size_t)r2 * DIM);
        dst = (ushort4*)(Wb + (size_t)r2 * DIM);
        sq  = w2 + r2;
    }
    float s = 0.f;
    #pragma unroll
    for (int c = 0; c < 4; ++c) {
        float4 v = src[c * 64 + lane];
        s += v.x * v.x + v.y * v.y + v.z * v.z + v.w * v.w;
        ushort4 o = { f32_to_bf16(v.x), f32_to_bf16(v.y),
                      f32_to_bf16(v.z), f32_to_bf16(v.w) };
        dst[c * 64 + lane] = o;
    }
    #pragma unroll
    for (int d = 1; d < 64; d <<= 1) s += __shfl_xor(s, d);
    if (lane == 0) *sq = s;
}

// ---------- Kernel 2: 256x256-tile 8-phase bf16 MFMA GEMM -> d2 + argmin partials ----------
// 512 threads = 8 waves (2M x 4N); per-wave C = 128x64 (8x4 frags of 16x16).
// BK=64 (2 kslices of 32). LDS 128KB: [dbuf 2][A/B][half 2][128 rows][64 cols bf16],
// XOR-swizzled q ^= ((q>>7)&7)<<4 (both staging-source and ds_read side).
__global__ __launch_bounds__(512, 2) void k_gemm256(
    const ushort_t* __restrict__ Xb, const ushort_t* __restrict__ Wb,
    const float* __restrict__ x2, const float* __restrict__ w2,
    ushort_t* __restrict__ d2, float* __restrict__ pmin, int* __restrict__ pidx) {
    __shared__ __attribute__((aligned(1024))) unsigned char ldsb[131072];

    const int tid  = threadIdx.x;
    const int lane = tid & 63;
    const int w    = tid >> 6;
    const int wr   = w >> 2;      // 0..1  (M)
    const int wc   = w & 3;       // 0..3  (N)
    const int lc   = lane & 15;
    const int lr16 = lane >> 4;   // 0..3

    // XCD-bijective block swizzle (1024 % 8 == 0)
    const int bid = blockIdx.x;
    const int swz = (bid & 7) * 128 + (bid >> 3);
    const int tn  = swz >> 4;     // 0..63
    const int tm  = swz & 15;     // 0..15

    // ds_read address tails (swizzle: within q = r*128 + cB, cB ^= ((r&7)<<4); r&7 == lc&7)
    const int smask = (lc & 7) << 4;
    const int tail0 = lc * 128 + ((lr16 * 16) ^ smask);        // kslice 0
    const int tail1 = lc * 128 + ((64 + lr16 * 16) ^ smask);   // kslice 1
    const int aoff  = wr * 16384;
    const int boff  = 32768 + (wc >> 1) * 16384 + (wc & 1) * 8192;

    // staging: thread covers 16B at p = i*8192 + tid*16; inverse-swizzled source coords
    int rS[2], cS[2];
    #pragma unroll
    for (int i = 0; i < 2; ++i) {
        int p = i * 8192 + tid * 16;
        rS[i] = p >> 7;                                        // swz preserves bits >= 7
        cS[i] = (((p & 127) ^ (((p >> 7) & 7) << 4)) >> 1);    // element offset in row
    }
    const size_t aRow = (size_t)tm * 256;
    const size_t bRow = (size_t)tn * 256;

    #define STAGE(kt, d, ab, h) do {                                            \
        const ushort_t* _g = (ab) ? Wb : Xb;                                     \
        const size_t _rb = ((ab) ? bRow : aRow) + (h) * 128;                     \
        _Pragma("unroll")                                                        \
        for (int _i = 0; _i < 2; ++_i)                                           \
            gload_lds16(_g + (_rb + rS[_i]) * DIM + (kt) * 64 + cS[_i],          \
                        ldsb + (d) * 65536 + (ab) * 32768 + (h) * 16384          \
                             + _i * 8192 + tid * 16);                            \
    } while (0)

    short8 aF[2][2][4];   // [mq][ks][mi]
    short8 bF[2][4];      // [ks][ni]
    f32x4  acc[8][4];
    #pragma unroll
    for (int i = 0; i < 8; ++i)
        #pragma unroll
        for (int j = 0; j < 4; ++j) acc[i][j] = (f32x4)0.f;

    #define LOAD_A(d, mq, ks, TAIL) do { _Pragma("unroll")                       \
        for (int _mi = 0; _mi < 4; ++_mi)                                        \
            aF[mq][ks][_mi] = *(const short8*)(ldsb + (d) * 65536 + aoff         \
                                + ((mq) * 4 + _mi) * 2048 + (TAIL)); } while (0)
    #define LOAD_B(d, ks, TAIL) do { _Pragma("unroll")                           \
        for (int _ni = 0; _ni < 4; ++_ni)                                        \
            bF[ks][_ni] = *(const short8*)(ldsb + (d) * 65536 + boff             \
                                + _ni * 2048 + (TAIL)); } while (0)
    #define MFMA_PH(mq, ks) do {                                                 \
        __builtin_amdgcn_s_setprio(1);                                           \
        _Pragma("unroll")                                                        \
        for (int _mi = 0; _mi < 4; ++_mi) { _Pragma("unroll")                    \
            for (int _ni = 0; _ni < 4; ++_ni)                                    \
                acc[(mq) * 4 + _mi][_ni] = __builtin_amdgcn_mfma_f32_16x16x32_bf16( \
                    aF[mq][ks][_mi], bF[ks][_ni], acc[(mq) * 4 + _mi][_ni], 0, 0, 0); } \
        __builtin_amdgcn_s_setprio(0); } while (0)
    #define BAR() __builtin_amdgcn_s_barrier()
    #define WAITLGKM() do { asm volatile("s_waitcnt lgkmcnt(0)" ::: "memory");   \
        __builtin_amdgcn_sched_barrier(0); } while (0)

    // ---- prologue: K0 all 4 half-tiles, K1 {Ah0, Ah1, Bh0} ----
    STAGE(0, 0, 0, 0); STAGE(0, 0, 0, 1); STAGE(0, 0, 1, 0); STAGE(0, 0, 1, 1);
    STAGE(1, 1, 0, 0); STAGE(1, 1, 0, 1); STAGE(1, 1, 1, 0);
    asm volatile("s_waitcnt vmcnt(6)" ::: "memory");   // K0 landed
    BAR();

    for (int it = 0; it < 8; ++it) {
        const int  ktA = 2 * it + 2;   // next dbuf0 K-tile
        const int  ktB = 2 * it + 3;   // next dbuf1 K-tile
        const bool pf  = (it < 7);
        // ---- g0: dbuf0, mq0 x ks0 ----
        LOAD_A(0, 0, 0, tail0); LOAD_A(0, 0, 1, tail1); LOAD_B(0, 0, tail0);
        STAGE(2 * it + 1, 1, 1, 1);           // complete current dbuf1 K-tile (Bh1)
        BAR(); WAITLGKM(); MFMA_PH(0, 0); BAR();
        // ---- g1: mq1 x ks0 ----
        LOAD_A(0, 1, 0, tail0); LOAD_A(0, 1, 1, tail1);
        BAR(); WAITLGKM(); MFMA_PH(1, 0); BAR();
        // ---- g2: mq0 x ks1 ----
        LOAD_B(0, 1, tail1);
        if (pf) { STAGE(ktA, 0, 0, 0); STAGE(ktA, 0, 0, 1); }   // A halves (dead since g1)
        BAR(); WAITLGKM(); MFMA_PH(0, 1); BAR();
        // ---- g3: mq1 x ks1 ; gate for dbuf1 reads ----
        if (pf) { STAGE(ktA, 0, 1, 0);
                  asm volatile("s_waitcnt vmcnt(6)" ::: "memory"); }
        else    { asm volatile("s_waitcnt vmcnt(0)" ::: "memory"); }
        BAR(); WAITLGKM(); MFMA_PH(1, 1); BAR();
        // ---- g4: dbuf1, mq0 x ks0 ----
        LOAD_A(1, 0, 0, tail0); LOAD_A(1, 0, 1, tail1); LOAD_B(1, 0, tail0);
        if (pf) STAGE(ktA, 0, 1, 1);
        BAR(); WAITLGKM(); MFMA_PH(0, 0); BAR();
        // ---- g5 ----
        LOAD_A(1, 1, 0, tail0); LOAD_A(1, 1, 1, tail1);
        BAR(); WAITLGKM(); MFMA_PH(1, 0); BAR();
        // ---- g6 ----
        LOAD_B(1, 1, tail1);
        if (pf) { STAGE(ktB, 1, 0, 0); STAGE(ktB, 1, 0, 1); }
        BAR(); WAITLGKM(); MFMA_PH(0, 1); BAR();
        // ---- g7 ; gate for next-iter dbuf0 reads ----
        if (pf) { STAGE(ktB, 1, 1, 0);
                  asm volatile("s_waitcnt vmcnt(6)" ::: "memory"); }
        BAR(); WAITLGKM(); MFMA_PH(1, 1); BAR();
    }

    // ---- epilogue: d2 = x2 - 2*dot + w2 (bf16), per-row min over this block's 256 cols ----
    float* smin = (float*)ldsb;            // [256][4]
    int*   sidx = (int*)(ldsb + 4096);     // [256][4]
    const int colb = tn * 256 + wc * 64 + lc;
    float w2c[4];
    #pragma unroll
    for (int ni = 0; ni < 4; ++ni) w2c[ni] = w2[colb + ni * 16];

    #pragma unroll
    for (int a = 0; a < 8; ++a) {
        #pragma unroll
        for (int rg = 0; rg < 4; ++rg) {
            const int rloc = wr * 128 + a * 16 + lr16 * 4 + rg;
            const int row  = tm * 256 + rloc;
            const float xx = x2[row];
            ushort_t* dst = d2 + (size_t)row * MN + colb;
            float dv[4];
            #pragma unroll
            for (int ni = 0; ni < 4; ++ni) {
                dv[ni] = xx - 2.f * acc[a][ni][rg] + w2c[ni];
                dst[ni * 16] = f32_to_bf16(dv[ni]);
            }
            float mn = dv[0]; int ix = colb;
            #pragma unroll
            for (int ni = 1; ni < 4; ++ni)
                if (dv[ni] < mn) { mn = dv[ni]; ix = colb + ni * 16; }
            #pragma unroll
            for (int d = 1; d < 16; d <<= 1) {
                float om = __shfl_xor(mn, d);
                int   oi = __shfl_xor(ix, d);
                if (om < mn || (om == mn && oi < ix)) { mn = om; ix = oi; }
            }
            if (lc == 0) { smin[rloc * 4 + wc] = mn; sidx[rloc * 4 + wc] = ix; }
        }
    }
    __syncthreads();
    if (tid < 256) {
        float mn = smin[tid * 4]; int ix = sidx[tid * 4];
        #pragma unroll
        for (int c = 1; c < 4; ++c) {
            float om = smin[tid * 4 + c]; int oi = sidx[tid * 4 + c];
            if (om < mn || (om == mn && oi < ix)) { mn = om; ix = oi; }
        }
        const int row = tm * 256 + tid;
        pmin[(size_t)row * NJB + tn] = mn;
        pidx[(size_t)row * NJB + tn] = ix;
    }
    #undef STAGE
    #undef LOAD_A
    #undef LOAD_B
    #undef MFMA_PH
    #undef BAR
    #undef WAITLGKM
}

// ---------- Kernel 3: reduce 64 partials/row -> bmu ----------
__global__ __launch_bounds__(256) void k_argmin(
    const float* __restrict__ pmin, const int* __restrict__ pidx,
    int* __restrict__ bmu) {
    int row  = blockIdx.x * 4 + (threadIdx.x >> 6);
    int lane = threadIdx.x & 63;
    const float* pm = pmin + (size_t)row * NJB;
    const int*   pi = pidx + (size_t)row * NJB;
    float m0 = pm[lane]; int i0 = pi[lane];
    #pragma unroll
    for (int d = 1; d < 64; d <<= 1) {
        float om = __shfl_xor(m0, d);
        int   oi = __shfl_xor(i0, d);
        if (om < m0 || (om == m0 && oi < i0)) { m0 = om; i0 = oi; }
    }
    if (lane == 0) bmu[row] = i0;
}

// ---------- Kernel 4: influence-weighted row sum ----------
__global__ __launch_bounds__(256) void k_loss(
    const ushort_t* __restrict__ d2, const int* __restrict__ bmu,
    float* __restrict__ lossb) {
    __shared__ float etab[255];
    __shared__ float red[4];
    int t = threadIdx.x;
    if (t < 255) etab[t] = __expf(-(float)(t * t) * 1e-4f);  // exp(-r^2/T^2), T=100
    __syncthreads();
    int row = blockIdx.x;
    int bl = bmu[row];
    int bi = bl >> 7, bj = bl & 127;
    const ushort_t* dr = d2 + (size_t)row * MN;
    float s = 0.f;
    #pragma unroll
    for (int c = 0; c < 8; ++c) {
        int j = c * 2048 + t * 8;
        short8 v = *(const short8*)&dr[j];
        int di = abs((j >> 7) - bi);
        int jc = j & 127;
        #pragma unroll
        for (int u = 0; u < 8; ++u) {
            int mh = di + abs(jc + u - bj);
            s += bf16_to_f32((ushort_t)v[u]) * etab[mh];
        }
    }
    #pragma unroll
    for (int d = 1; d < 64; d <<= 1) s += __shfl_xor(s, d);
    if ((t & 63) == 0) red[t >> 6] = s;
    __syncthreads();
    if (t == 0) lossb[row] = red[0] + red[1] + red[2] + red[3];
}

// ---------- Kernel 5: final deterministic reduce ----------
__global__ __launch_bounds__(256) void k_final(
    const float* __restrict__ lossb, float* __restrict__ out) {
    __shared__ float red[4];
    int t = threadIdx.x;
    float s = 0.f;
    #pragma unroll
    for (int k = 0; k < 16; ++k) s += lossb[t + k * 256];
    #pragma unroll
    for (int d = 1; d < 64; d <<= 1) s += __shfl_xor(s, d);
    if ((t & 63) == 0) red[t >> 6] = s;
    __syncthreads();
    if (t == 0) out[0] = (red[0] + red[1] + red[2] + red[3]) * (1.0f / 128.0f);
}

extern "C" void kernel_launch(void* const* d_in, const int* in_sizes, int n_in,
                              void* d_out, int out_size, void* d_ws, size_t ws_size,
                              hipStream_t stream) {
    const float* X = (const float*)d_in[0];
    const float* W = (const float*)d_in[1];
    unsigned char* ws = (unsigned char*)d_ws;
    ushort_t* Xb   = (ushort_t*)(ws);
    ushort_t* Wb   = (ushort_t*)(ws + 8388608);
    float*    x2   = (float*)(ws + 41943040);
    float*    w2   = (float*)(ws + 41959424);
    ushort_t* d2   = (ushort_t*)(ws + 42024960);
    float*    pmin = (float*)(ws + 176242688);
    int*      pidx = (int*)(ws + 178339840);
    int*      bmu  = (int*)(ws + 180436992);
    float*    lossb= (float*)(ws + 180453376);

    k_convert<<<5120, 256, 0, stream>>>(X, W, Xb, Wb, x2, w2);
    k_gemm256<<<1024, 512, 0, stream>>>(Xb, Wb, x2, w2, d2, pmin, pidx);
    k_argmin<<<1024, 256, 0, stream>>>(pmin, pidx, bmu);
    k_loss<<<4096, 256, 0, stream>>>(d2, bmu, lossb);
    k_final<<<1, 256, 0, stream>>>(lossb, (float*)d_out);
}

// Round 3
// 202.378 us; speedup vs baseline: 1.2779x; 1.1163x over previous
//
#include <hip/hip_runtime.h>

// SOM loss, MI355X. Dims fixed: B=4096, D=1024, m=n=128, T=100.
// ws layout:
//   Xb   bf16[4096][1024]        @ 0
//   Wb   bf16[16384][1024]       @ 8388608
//   x2   f32[4096]               @ 41943040
//   w2   f32[16384]              @ 41959424
//   d2   bf16[4096][16384]       @ 42024960
//   pmin f32[4096][64]           @ 176242688
//   pidx i32[4096][64]           @ 178339840
//   lossb f32[4096]              @ 180453376

typedef __attribute__((ext_vector_type(8))) short short8;
typedef __attribute__((ext_vector_type(4))) float f32x4;
typedef unsigned short ushort_t;

#define B_ROWS 4096
#define DIM    1024
#define MN     16384
#define NJB    64

__device__ static inline ushort_t f32_to_bf16(float f) {
    unsigned u = __float_as_uint(f);
    u = (u + 0x7FFFu + ((u >> 16) & 1u)) >> 16;   // RTN-even
    return (ushort_t)u;
}
__device__ static inline float bf16_to_f32(ushort_t h) {
    return __uint_as_float(((unsigned)h) << 16);
}
__device__ static inline void gload_lds16(const void* g, void* l) {
    __builtin_amdgcn_global_load_lds(
        (const __attribute__((address_space(1))) unsigned*)g,
        (__attribute__((address_space(3))) unsigned*)l, 16, 0, 0);
}

// ---------- Kernel 1: f32 -> bf16 conversion + row sum-of-squares ----------
__global__ __launch_bounds__(256) void k_convert(
    const float* __restrict__ X, const float* __restrict__ W,
    ushort_t* __restrict__ Xb, ushort_t* __restrict__ Wb,
    float* __restrict__ x2, float* __restrict__ w2) {
    int row  = blockIdx.x * 4 + (threadIdx.x >> 6);
    int lane = threadIdx.x & 63;
    const float4* src;
    ushort4* dst;
    float* sq;
    if (row < B_ROWS) {
        src = (const float4*)(X + (size_t)row * DIM);
        dst = (ushort4*)(Xb + (size_t)row * DIM);
        sq  = x2 + row;
    } else {
        int r2 = row - B_ROWS;
        src = (const float4*)(W + (size_t)r2 * DIM);
        dst = (ushort4*)(Wb + (size_t)r2 * DIM);
        sq  = w2 + r2;
    }
    float s = 0.f;
    #pragma unroll
    for (int c = 0; c < 4; ++c) {
        float4 v = src[c * 64 + lane];
        s += v.x * v.x + v.y * v.y + v.z * v.z + v.w * v.w;
        ushort4 o = { f32_to_bf16(v.x), f32_to_bf16(v.y),
                      f32_to_bf16(v.z), f32_to_bf16(v.w) };
        dst[c * 64 + lane] = o;
    }
    #pragma unroll
    for (int d = 1; d < 64; d <<= 1) s += __shfl_xor(s, d);
    if (lane == 0) *sq = s;
}

// ---------- Kernel 2: 256x256-tile 8-phase GEMM, read-ahead + counted lgkm ----------
// 512 thr = 8 waves (2M x 4N). Swapped MFMA operands: acc frag [i][ni] =
// mfma(Wfrag ni, Xfrag i, .) so D rows = W-index, D cols = X-index: per-lane
// 4 consecutive d2 columns -> packed ushort4 stores.
__global__ __launch_bounds__(512, 2) void k_gemm256(
    const ushort_t* __restrict__ Xb, const ushort_t* __restrict__ Wb,
    const float* __restrict__ x2, const float* __restrict__ w2,
    ushort_t* __restrict__ d2, float* __restrict__ pmin, int* __restrict__ pidx) {
    __shared__ __attribute__((aligned(1024))) unsigned char ldsb[131072];

    const int tid  = threadIdx.x;
    const int lane = tid & 63;
    const int w    = tid >> 6;
    const int wr   = w >> 2;      // 0..1  (X-row half)
    const int wc   = w & 3;       // 0..3  (W-col quarter)
    const int lc   = lane & 15;
    const int lr16 = lane >> 4;   // 0..3

    // XCD-bijective block swizzle (1024 % 8 == 0)
    const int bid = blockIdx.x;
    const int swz = (bid & 7) * 128 + (bid >> 3);
    const int tn  = swz >> 4;     // 0..63  W-tile
    const int tm  = swz & 15;     // 0..15  X-tile

    // ds_read tails (row r: byte col ^= ((r&7)<<4); r&7 == lc&7)
    const int smask = (lc & 7) << 4;
    const int tail0 = lc * 128 + ((lr16 * 16) ^ smask);        // kslice 0
    const int tail1 = lc * 128 + ((64 + lr16 * 16) ^ smask);   // kslice 1

    // staging: thread covers 16B at p = i*8192 + tid*16; inverse-swizzled source
    int rS[2], cS[2];
    #pragma unroll
    for (int i = 0; i < 2; ++i) {
        int p = i * 8192 + tid * 16;
        rS[i] = p >> 7;
        cS[i] = (((p & 127) ^ (((p >> 7) & 7) << 4)) >> 1);
    }
    const size_t aRow = (size_t)tm * 256;
    const size_t bRow = (size_t)tn * 256;

    #define STAGE(kt, d, ab, h) do {                                            \
        const ushort_t* _g = (ab) ? Wb : Xb;                                     \
        const size_t _rb = ((ab) ? bRow : aRow) + (h) * 128;                     \
        _Pragma("unroll")                                                        \
        for (int _i = 0; _i < 2; ++_i)                                           \
            gload_lds16(_g + (_rb + rS[_i]) * DIM + (kt) * 64 + cS[_i],          \
                        ldsb + (d) * 65536 + (ab) * 32768 + (h) * 16384          \
                             + _i * 8192 + tid * 16);                            \
    } while (0)

    short8 wfA[4], wfB[4], xf0[4], xf4[4];
    f32x4  acc[8][4];
    #pragma unroll
    for (int i = 0; i < 8; ++i)
        #pragma unroll
        for (int j = 0; j < 4; ++j) acc[i][j] = (f32x4)0.f;

    #define LDW(d, DST, TAIL) do { _Pragma("unroll")                             \
        for (int _n = 0; _n < 4; ++_n)                                           \
            DST[_n] = *(const short8*)(ldsb + (d) * 65536 + 32768 + wc * 8192    \
                                + _n * 2048 + (TAIL)); } while (0)
    #define LDX(d, DST, I0, TAIL) do { _Pragma("unroll")                         \
        for (int _m = 0; _m < 4; ++_m)                                           \
            DST[_m] = *(const short8*)(ldsb + (d) * 65536 + wr * 16384           \
                                + ((I0) + _m) * 2048 + (TAIL)); } while (0)
    #define PH(WFV, XFV, IB) do {                                                \
        __builtin_amdgcn_s_setprio(1);                                           \
        _Pragma("unroll")                                                        \
        for (int _m = 0; _m < 4; ++_m) { _Pragma("unroll")                       \
            for (int _n = 0; _n < 4; ++_n)                                       \
                acc[(IB) + _m][_n] = __builtin_amdgcn_mfma_f32_16x16x32_bf16(    \
                    WFV[_n], XFV[_m], acc[(IB) + _m][_n], 0, 0, 0); }            \
        __builtin_amdgcn_s_setprio(0); } while (0)
    #define BAR() __builtin_amdgcn_s_barrier()
    #define WLG(n) do { asm volatile("s_waitcnt lgkmcnt(" #n ")" ::: "memory");  \
        __builtin_amdgcn_sched_barrier(0); } while (0)
    #define GATE() asm volatile("s_waitcnt vmcnt(0)" ::: "memory")

    // ---- prologue: T0 -> dbuf0 ----
    STAGE(0, 0, 0, 0); STAGE(0, 0, 0, 1); STAGE(0, 0, 1, 0); STAGE(0, 0, 1, 1);
    GATE();
    BAR();

    for (int it = 0; it < 8; ++it) {
        const int  T1  = 2 * it + 1;   // -> dbuf1, read g4-g7 this iter
        const int  T0n = 2 * it + 2;   // -> dbuf0, read next iter
        const bool pf  = (it < 7);
        // g0: reads for P0+P1 (dbuf0 ks0); stage T1 A-halves
        LDW(0, wfA, tail0); LDX(0, xf0, 0, tail0); LDX(0, xf4, 4, tail0);
        STAGE(T1, 1, 0, 0); STAGE(T1, 1, 0, 1);
        BAR(); WLG(4); PH(wfA, xf0, 0); BAR();
        // g1: reads for P2 (ks1); stage T1 B-halves
        LDW(0, wfB, tail1); LDX(0, xf0, 0, tail1);
        STAGE(T1, 1, 1, 0); STAGE(T1, 1, 1, 1);
        BAR(); WLG(8); PH(wfA, xf4, 4); BAR();
        // g2: reads for P3
        LDX(0, xf4, 4, tail1);
        BAR(); WLG(4); PH(wfB, xf0, 0); BAR();
        // g3: gate T1 (own loads; BAR covers other waves)
        GATE();
        BAR(); WLG(0); PH(wfB, xf4, 4); BAR();
        // g4: reads for P4+P5 (dbuf1 ks0); stage T0n A-halves
        LDW(1, wfA, tail0); LDX(1, xf0, 0, tail0); LDX(1, xf4, 4, tail0);
        if (pf) { STAGE(T0n, 0, 0, 0); STAGE(T0n, 0, 0, 1); }
        BAR(); WLG(4); PH(wfA, xf0, 0); BAR();
        // g5: reads for P6; stage T0n B-halves
        LDW(1, wfB, tail1); LDX(1, xf0, 0, tail1);
        if (pf) { STAGE(T0n, 0, 1, 0); STAGE(T0n, 0, 1, 1); }
        BAR(); WLG(8); PH(wfA, xf4, 4); BAR();
        // g6: reads for P7
        LDX(1, xf4, 4, tail1);
        BAR(); WLG(4); PH(wfB, xf0, 0); BAR();
        // g7: gate T0n
        if (pf) GATE();
        BAR(); WLG(0); PH(wfB, xf4, 4); BAR();
    }

    // ---- epilogue: d2 = x2 - 2*dot + w2 (packed ushort4), per-row argmin ----
    float* smin = (float*)ldsb;            // [256][4]
    int*   sidx = (int*)(ldsb + 4096);     // [256][4]
    const int colw = tn * 256 + wc * 64;   // wave's W-col base
    float4 w2q[4];
    #pragma unroll
    for (int ni = 0; ni < 4; ++ni)
        w2q[ni] = *(const float4*)(w2 + colw + ni * 16 + lr16 * 4);

    #pragma unroll
    for (int i = 0; i < 8; ++i) {
        const int rloc = wr * 128 + i * 16 + lc;
        const int row  = tm * 256 + rloc;
        const float xx = x2[row];
        ushort_t* dst = d2 + (size_t)row * MN + colw;
        float mn = __builtin_inff(); int ix = 0x7fffffff;
        #pragma unroll
        for (int ni = 0; ni < 4; ++ni) {
            const int l0 = ni * 16 + lr16 * 4;
            float dv[4];
            ushort4 st;
            #pragma unroll
            for (int rg = 0; rg < 4; ++rg) {
                dv[rg] = xx - 2.f * acc[i][ni][rg] + w2q[ni][rg];
                st[rg] = (unsigned short)f32_to_bf16(dv[rg]);
            }
            *(ushort4*)(dst + l0) = st;
            #pragma unroll
            for (int rg = 0; rg < 4; ++rg) {
                const int cand = colw + l0 + rg;
                if (dv[rg] < mn || (dv[rg] == mn && cand < ix)) { mn = dv[rg]; ix = cand; }
            }
        }
        #pragma unroll
        for (int d = 16; d < 64; d <<= 1) {
            float om = __shfl_xor(mn, d);
            int   oi = __shfl_xor(ix, d);
            if (om < mn || (om == mn && oi < ix)) { mn = om; ix = oi; }
        }
        if (lane < 16) { smin[rloc * 4 + wc] = mn; sidx[rloc * 4 + wc] = ix; }
    }
    __syncthreads();
    if (tid < 256) {
        float mn = smin[tid * 4]; int ix = sidx[tid * 4];
        #pragma unroll
        for (int c = 1; c < 4; ++c) {
            float om = smin[tid * 4 + c]; int oi = sidx[tid * 4 + c];
            if (om < mn || (om == mn && oi < ix)) { mn = om; ix = oi; }
        }
        const int row = tm * 256 + tid;
        pmin[(size_t)row * NJB + tn] = mn;
        pidx[(size_t)row * NJB + tn] = ix;
    }
    #undef STAGE
    #undef LDW
    #undef LDX
    #undef PH
    #undef BAR
    #undef WLG
    #undef GATE
}

// ---------- Kernel 3: fused argmin-finish + influence-weighted row sum ----------
__global__ __launch_bounds__(256) void k_loss(
    const ushort_t* __restrict__ d2, const float* __restrict__ pmin,
    const int* __restrict__ pidx, float* __restrict__ lossb) {
    __shared__ float etab[255];
    __shared__ float red[4];
    __shared__ int bmu_s;
    int t = threadIdx.x;
    if (t < 255) etab[t] = __expf(-(float)(t * t) * 1e-4f);  // exp(-r^2/T^2), T=100
    int row = blockIdx.x;
    if (t < 64) {
        float m0 = pmin[(size_t)row * NJB + t];
        int   i0 = pidx[(size_t)row * NJB + t];
        #pragma unroll
        for (int d = 1; d < 64; d <<= 1) {
            float om = __shfl_xor(m0, d);
            int   oi = __shfl_xor(i0, d);
            if (om < m0 || (om == m0 && oi < i0)) { m0 = om; i0 = oi; }
        }
        if (t == 0) bmu_s = i0;
    }
    __syncthreads();
    int bl = bmu_s;
    int bi = bl >> 7, bj = bl & 127;
    const ushort_t* dr = d2 + (size_t)row * MN;
    float s = 0.f;
    #pragma unroll
    for (int c = 0; c < 8; ++c) {
        int j = c * 2048 + t * 8;
        short8 v = *(const short8*)&dr[j];
        int di = abs((j >> 7) - bi);
        int jc = j & 127;
        #pragma unroll
        for (int u = 0; u < 8; ++u) {
            int mh = di + abs(jc + u - bj);
            s += bf16_to_f32((ushort_t)v[u]) * etab[mh];
        }
    }
    #pragma unroll
    for (int d = 1; d < 64; d <<= 1) s += __shfl_xor(s, d);
    if ((t & 63) == 0) red[t >> 6] = s;
    __syncthreads();
    if (t == 0) lossb[row] = red[0] + red[1] + red[2] + red[3];
}

// ---------- Kernel 4: final deterministic reduce ----------
__global__ __launch_bounds__(256) void k_final(
    const float* __restrict__ lossb, float* __restrict__ out) {
    __shared__ float red[4];
    int t = threadIdx.x;
    float s = 0.f;
    #pragma unroll
    for (int k = 0; k < 16; ++k) s += lossb[t + k * 256];
    #pragma unroll
    for (int d = 1; d < 64; d <<= 1) s += __shfl_xor(s, d);
    if ((t & 63) == 0) red[t >> 6] = s;
    __syncthreads();
    if (t == 0) out[0] = (red[0] + red[1] + red[2] + red[3]) * (1.0f / 128.0f);
}

extern "C" void kernel_launch(void* const* d_in, const int* in_sizes, int n_in,
                              void* d_out, int out_size, void* d_ws, size_t ws_size,
                              hipStream_t stream) {
    const float* X = (const float*)d_in[0];
    const float* W = (const float*)d_in[1];
    unsigned char* ws = (unsigned char*)d_ws;
    ushort_t* Xb   = (ushort_t*)(ws);
    ushort_t* Wb   = (ushort_t*)(ws + 8388608);
    float*    x2   = (float*)(ws + 41943040);
    float*    w2   = (float*)(ws + 41959424);
    ushort_t* d2   = (ushort_t*)(ws + 42024960);
    float*    pmin = (float*)(ws + 176242688);
    int*      pidx = (int*)(ws + 178339840);
    float*    lossb= (float*)(ws + 180453376);

    k_convert<<<5120, 256, 0, stream>>>(X, W, Xb, Wb, x2, w2);
    k_gemm256<<<1024, 512, 0, stream>>>(Xb, Wb, x2, w2, d2, pmin, pidx);
    k_loss<<<4096, 256, 0, stream>>>(d2, pmin, pidx, lossb);
    k_final<<<1, 256, 0, stream>>>(lossb, (float*)d_out);
}